// Round 4
// baseline (83.251 us; speedup 1.0000x reference)
//
#include <hip/hip_runtime.h>

// out[i] = sum_k a[k] * tanh(5*(x[i]+b[k])), k=0..6
// tanh(z) = 1 - 2/(exp(2z)+1); exp(10*(x+b_k)) = E * c_k with E = exp2(SC*x),
// c_k = exp2(SC*b_k), SC = 10*log2(e).
// out = suma + sum_k (-2*a_k) / (E*c_k + 1)
// Pairwise combine: a/u + b/v = (a*v + b*u) * rcp(u*v)  -> 1 exp2 + 4 rcp per elem.
// Saturation-safe: E->inf => den=inf => rcp=0, finite numerator * 0 = 0 (true
// pair contribution also ->0; the +/-1 limits live in suma). E->0 => d->1 exact.

#define K_TERMS 7

__device__ __forceinline__ float fast_exp2(float x) { return __builtin_amdgcn_exp2f(x); }
__device__ __forceinline__ float fast_rcp(float x)  { return __builtin_amdgcn_rcpf(x); }

__global__ __launch_bounds__(256)
void quantizationLayer_49563922596433_kernel(const float* __restrict__ x,
                                             const float* __restrict__ w,
                                             float* __restrict__ out,
                                             int n4) {
    const float SC = 14.4269504088896f; // 10 * log2(e)

    // Uniform-address weight prep -> SGPRs.
    float suma = 0.f;
    float ck[K_TERMS], na2[K_TERMS];
#pragma unroll
    for (int k = 0; k < K_TERMS; ++k) {
        float a = w[2 * k + 0];
        float b = w[2 * k + 1];
        suma  += a;
        ck[k]  = fast_exp2(SC * b);
        na2[k] = -2.f * a;
    }

    int i = blockIdx.x * blockDim.x + threadIdx.x;
    if (i >= n4) return;

    float4 v = ((const float4*)x)[i];
    float in[4] = {v.x, v.y, v.z, v.w};
    float o[4];
#pragma unroll
    for (int j = 0; j < 4; ++j) {
        float E   = fast_exp2(in[j] * SC);   // one exp2 per element
        float acc = suma;
        // three pairs (0,1) (2,3) (4,5)
#pragma unroll
        for (int p = 0; p < 3; ++p) {
            int k0 = 2 * p, k1 = 2 * p + 1;
            float d0  = fmaf(E, ck[k0], 1.f);
            float d1  = fmaf(E, ck[k1], 1.f);
            float num = fmaf(na2[k1], d0, na2[k0] * d1);
            float den = d0 * d1;
            acc = fmaf(num, fast_rcp(den), acc);
        }
        // leftover term k=6
        float d6 = fmaf(E, ck[6], 1.f);
        acc = fmaf(na2[6], fast_rcp(d6), acc);
        o[j] = acc;
    }
    float4 ov = {o[0], o[1], o[2], o[3]};
    ((float4*)out)[i] = ov;
}

extern "C" void kernel_launch(void* const* d_in, const int* in_sizes, int n_in,
                              void* d_out, int out_size, void* d_ws, size_t ws_size,
                              hipStream_t stream) {
    const float* x = (const float*)d_in[0];
    const float* w = (const float*)d_in[1];
    float* out = (float*)d_out;

    int n  = in_sizes[0];      // 2048*4096 = 8388608, divisible by 4
    int n4 = n / 4;
    int block = 256;
    int grid = (n4 + block - 1) / block;  // 8192 blocks
    quantizationLayer_49563922596433_kernel<<<grid, block, 0, stream>>>(x, w, out, n4);
}